// Round 9
// baseline (493.588 us; speedup 1.0000x reference)
//
#include <hip/hip_runtime.h>
#include <cstdint>
#include <cstddef>

// ---------------------------------------------------------------------------
// GCN2: h = relu(x@W0+b0); 6x { agg = scatter_sum(w*h[src] -> dst);
//        z = 0.9*agg + 0.1*x0; h = relu(z @ ((1-b)I + b*Wc)) };
//        out = h@W1 + b1
// R0 871 ... R10 504 (XCD-pinned slab agg). R14 502. R16 501.
// R17 533 grid-stride (CLOSED). R18/R19 573 nt (CLOSED). R20 615 fusion
// (CLOSED; slab-L2 locality is THE asset). R21 800 degree sort (CLOSED).
// R22 475 WIN: degree padding x8. R23 468 small WIN: ep-load pipeline.
// R24 475 REGRESSION: single-pass bucket. FETCH -32MB as predicted BUT
// WRITE +20MB, dur 62->92: slice=b&7 IS XCD pinning for cur/ep WRITES
// (slice==XCD under round-robin). Sliced bucket restored; bucket CLOSED.
// R25 (this): 2-deep gather pipeline in agg (ping-pong A/B, no reg-move
// chains). Theory: VALU ~6us and line-throughput ~6us per dispatch, yet
// agg ~50us -> rounds serialize on gather latency. Gather round k+1 while
// FMA round k; ep loaded one phase ahead of gather. Round/FMA order
// unchanged -> bit-identical. Est VGPR ~100 (same 65-128 band as R23).
// Predict agg -15..25% each, total ~420-445. Regression -> revert R23,
// agg frozen permanently.
// ---------------------------------------------------------------------------

#define NN 50000
#define EE 800000

constexpr float ALPHA   = 0.1f;
constexpr float BETA_C  = 0.05406722127027574f;   // log(0.5/9 + 1)

constexpr int NB = (NN + 255) / 256;              // 196 scan blocks
constexpr int HB = (EE + 255) / 256;              // 3125 edge chunks
constexpr int PREP_TOT = 128 * 128 + 6 * 128 * 128 + 64 * 128;   // 122880
constexpr int PB = (PREP_TOT + 255) / 256;        // 480 prep blocks
constexpr int SLICE = NN / 8;                     // 6250 dst nodes per slice
constexpr int GA = (NN + 63) / 64;                // 782 gemm blocks / slab chunks
constexpr int AGGB = 8 * ((GA + 1) / 2);          // 3128 agg blocks (XCD-pinned)
constexpr int EPCAP = EE + 7 * NN + 16;           // padded slots + lookahead slack

typedef unsigned short u16;
typedef unsigned int   u32;
typedef __attribute__((ext_vector_type(8))) short short8;
typedef __attribute__((ext_vector_type(4))) float f32x4;

__device__ __forceinline__ float bf2f(u16 u) {
    union { float f; u32 i; } c; c.i = ((u32)u) << 16; return c.f;
}
__device__ __forceinline__ u16 f2bf(float f) {          // round-to-nearest-even
    union { float f; u32 i; } c; c.f = f;
    u32 r = c.i + 0x7fffu + ((c.i >> 16) & 1u);
    return (u16)(r >> 16);
}

// ------------- merged: histogram (blocks < HB) + weight prep (rest) ---------
__global__ void k_hist_prep(const int* __restrict__ edst, int* __restrict__ deg,
                            const float* __restrict__ W0, const float* __restrict__ cw,
                            const float* __restrict__ W1, u16* __restrict__ w0t,
                            u16* __restrict__ wft, u16* __restrict__ w1t, int E) {
    int b = blockIdx.x;
    if (b < HB) {
        int i = b * 256 + threadIdx.x;
        if (i < E) atomicAdd(&deg[edst[i]], 1);
    } else {
        int i = (b - HB) * 256 + threadIdx.x;
        if (i < 16384) {
            int n = i >> 7, k = i & 127;
            w0t[i] = f2bf(W0[k * 128 + n]);
        } else if (i < 16384 + 6 * 16384) {
            int r = i - 16384;
            int l = r >> 14; int t = r & 16383;
            int n = t >> 7, k = t & 127;
            float v = BETA_C * cw[l * 16384 + k * 128 + n]
                      + ((k == n) ? (1.f - BETA_C) : 0.f);
            wft[r] = f2bf(v);
        } else if (i < PREP_TOT) {
            int r = i - (16384 + 6 * 16384);
            int n = r >> 7, k = r & 127;
            w1t[r] = f2bf(W1[k * 64 + n]);
        }
    }
}

// ---------------- single-dispatch scan: publish-first parallel lookback -----
// Scans PADDED degrees ((deg+7)&~7); bucket fills real edges, pads zeroed.
__global__ __launch_bounds__(256) void k_scan_lb(const int* __restrict__ deg,
                                                 int* __restrict__ bsum,
                                                 int* __restrict__ offs,
                                                 int* __restrict__ cur) {
    __shared__ int sh[256];
    __shared__ int sw[4];
    const int c = blockIdx.x, tid = threadIdx.x;
    const int i = c * 256 + tid;
    int v = (i < NN) ? ((deg[i] + 7) & ~7) : 0;
    sh[tid] = v;
    __syncthreads();
#pragma unroll
    for (int o = 1; o < 256; o <<= 1) {
        int u = (tid >= o) ? sh[tid - o] : 0;
        __syncthreads();
        sh[tid] += u;
        __syncthreads();
    }
    if (tid == 255) atomicExch(&bsum[c], sh[255] + 1);   // publish (nonzero)
    int part = 0;
    for (int t = tid; t < c; t += 256) {                 // parallel lookback
        int b;
        do { b = atomicAdd(&bsum[t], 0); } while (b == 0);
        part += b - 1;
    }
#pragma unroll
    for (int o = 32; o > 0; o >>= 1) part += __shfl_down(part, o);
    if ((tid & 63) == 0) sw[tid >> 6] = part;
    __syncthreads();
    const int base = sw[0] + sw[1] + sw[2] + sw[3];
    const int ex = base + sh[tid] - v;
    if (i < NN) {
        offs[i] = ex;
        cur[i]  = ex;
        if (i == NN - 1) offs[NN] = ex + v;
    }
}

// ---- layer-0 GEMM tile body (x fp32 row-major -> relu(x@W0+b0) bf16 slab) --
__device__ __forceinline__ void gemm0_tile(int t, const float* __restrict__ x,
                                           const u16* __restrict__ w0t,
                                           const float* __restrict__ b0,
                                           u16* __restrict__ x0s) {
    const int lane = threadIdx.x & 63;
    const int wave = threadIdx.x >> 6;
    const int q = lane >> 4;
    const int m16 = lane & 15;
    const int node = t * 64 + wave * 16 + m16;
    const int nload = node < NN ? node : NN - 1;

    short8 zf[4];
    const float* xp = x + (size_t)nload * 128 + q * 8;
#pragma unroll
    for (int s = 0; s < 4; ++s) {
        float4 u0 = *(const float4*)(xp + s * 32);
        float4 u1 = *(const float4*)(xp + s * 32 + 4);
        short8 z;
        z[0] = (short)f2bf(u0.x); z[1] = (short)f2bf(u0.y);
        z[2] = (short)f2bf(u0.z); z[3] = (short)f2bf(u0.w);
        z[4] = (short)f2bf(u1.x); z[5] = (short)f2bf(u1.y);
        z[6] = (short)f2bf(u1.z); z[7] = (short)f2bf(u1.w);
        zf[s] = z;
    }

    f32x4 acc[8];
#pragma unroll
    for (int c = 0; c < 8; ++c) {
        f32x4 a = {0.f, 0.f, 0.f, 0.f};
        const u16* wp = w0t + (size_t)(c * 16 + m16) * 128 + q * 8;
#pragma unroll
        for (int s = 0; s < 4; ++s) {
            short8 wf = *(const short8*)(wp + s * 32);
            a = __builtin_amdgcn_mfma_f32_16x16x32_bf16(wf, zf[s], a, 0, 0, 0);
        }
        acc[c] = a;
    }

    if (node < NN) {
#pragma unroll
        for (int c = 0; c < 8; ++c) {
            const int f0 = c * 16 + q * 4;
            float4 bv = *(const float4*)(b0 + f0);
            float v0 = acc[c][0] + bv.x; v0 = v0 > 0.f ? v0 : 0.f;
            float v1 = acc[c][1] + bv.y; v1 = v1 > 0.f ? v1 : 0.f;
            float v2 = acc[c][2] + bv.z; v2 = v2 > 0.f ? v2 : 0.f;
            float v3 = acc[c][3] + bv.w; v3 = v3 > 0.f ? v3 : 0.f;
            ushort4 o;
            o.x = f2bf(v0); o.y = f2bf(v1); o.z = f2bf(v2); o.w = f2bf(v3);
            *(ushort4*)(x0s + (size_t)(f0 >> 5) * NN * 32
                        + (size_t)node * 32 + (f0 & 31)) = o;
        }
    }
}

// ------ merged: 8-way dst-sliced bucket scatter + layer-0 GEMM (indep) ------
// slice = b&7 == XCD under round-robin dispatch -> cur/ep writes L2-local.
__global__ __launch_bounds__(256) void k_bucket_g0(const int* __restrict__ src,
                                                   const int* __restrict__ dst,
                                                   const float* __restrict__ w,
                                                   int* __restrict__ cur,
                                                   u32* __restrict__ ep,
                                                   const float* __restrict__ x,
                                                   const u16* __restrict__ w0t,
                                                   const float* __restrict__ b0,
                                                   u16* __restrict__ x0s, int E) {
    const int b = blockIdx.x;
    if (b < HB * 8) {
        const int slice = b & 7;
        const int i = (b >> 3) * 256 + threadIdx.x;
        if (i >= E) return;
        const int d = dst[i];
        const int lo = slice * SLICE;
        if (d >= lo && d < lo + SLICE) {
            int pos = atomicAdd(&cur[d], 1);
            ep[pos] = ((u32)f2bf(w[i]) << 16) | (u32)src[i];
        }
    } else {
        gemm0_tile(b - HB * 8, x, w0t, b0, x0s);
    }
}

// ------- XCD-pinned slab aggregate + z-fold (R25: 2-deep gather pipeline) ---
// Slab layout F[s][n][32] bf16; slab=(bid&7)>>1 -> XCD pair owns one 3.2MB
// slab (L2-resident). Wave = 16 consecutive nodes x 4 lanes (uint4 row part).
// Ranges exact multiples of 8 (R22 padding; pads w=0 -> +0.0f exact).
// Ping-pong A/B phases: gather round k+1 while FMA round k; ep loaded one
// phase ahead of its gather. FMA round order and j-order unchanged.
#define AGG_LOADR(R, E0)                                                      \
    _Pragma("unroll")                                                         \
    for (int j = 0; j < 8; ++j) R[j] = ep[(E0) + j];
#define AGG_GATHER(V, R)                                                      \
    _Pragma("unroll")                                                         \
    for (int j = 0; j < 8; ++j)                                               \
        V[j] = table[(size_t)(R[j] & 0xffffu) * 4 + f4];
#define AGG_FMA8(R, V)                                                        \
    _Pragma("unroll")                                                         \
    for (int j = 0; j < 8; ++j) {                                             \
        float w = bf2f((u16)(R[j] >> 16));                                    \
        a0 += w * bf2f((u16)V[j].x);  a1 += w * bf2f((u16)(V[j].x >> 16));    \
        a2 += w * bf2f((u16)V[j].y);  a3 += w * bf2f((u16)(V[j].y >> 16));    \
        a4 += w * bf2f((u16)V[j].z);  a5 += w * bf2f((u16)(V[j].z >> 16));    \
        a6 += w * bf2f((u16)V[j].w);  a7 += w * bf2f((u16)(V[j].w >> 16));    \
    }

__global__ __launch_bounds__(256) void k_agg_z(const int* __restrict__ offs,
                                               const u32* __restrict__ ep,
                                               const u16* __restrict__ hs,
                                               const u16* __restrict__ x0s,
                                               u16* __restrict__ zs) {
    const int bid = blockIdx.x;
    const int s     = (bid & 7) >> 1;
    const int chunk = ((bid >> 3) << 1) | (bid & 1);     // 0..781
    const int lane = threadIdx.x & 63;
    const int wave = threadIdx.x >> 6;
    const int g  = lane >> 2;          // node group 0..15
    const int f4 = lane & 3;           // uint4 index within 64B slab row
    const int n  = chunk * 64 + wave * 16 + g;
    const int nc = n < NN ? n : NN - 1;
    const uint4* table = (const uint4*)(hs + (size_t)s * NN * 32);

    const int beg = offs[nc], end = offs[nc + 1];
    const int nr = (end - beg) >> 3;   // rounds (padding => exact)
    float a0 = 0.f, a1 = 0.f, a2 = 0.f, a3 = 0.f;
    float a4 = 0.f, a5 = 0.f, a6 = 0.f, a7 = 0.f;

    if (nr > 0) {
        u32 rA[8], rB[8]; uint4 vA[8], vB[8];
        AGG_LOADR(rA, beg);                    // ep round 0
        AGG_LOADR(rB, beg + 8);                // ep round 1 (junk ok if nr==1)
        AGG_GATHER(vA, rA);                    // gather round 0
        int e2 = beg + 16;                     // ep offset of round k+2
        int k = 0;
        // invariant: vA=gather(k), rA=ep(k), rB=ep(k+1)
        while (k + 3 < nr) {
            // phase A: round k
            AGG_GATHER(vB, rB);                // gather k+1
            AGG_FMA8(rA, vA);                  // FMA k
            AGG_LOADR(rA, e2); e2 += 8;        // ep k+2
            // phase B: round k+1
            AGG_GATHER(vA, rA);                // gather k+2
            AGG_FMA8(rB, vB);                  // FMA k+1
            AGG_LOADR(rB, e2); e2 += 8;        // ep k+3 (junk ok at range end)
            k += 2;
        }
        // remaining rounds: nr-k in {1,2,3}; state per invariant
        if (k + 2 < nr) {                      // 3 left: rounds k,k+1,k+2
            AGG_GATHER(vB, rB);
            AGG_FMA8(rA, vA);                  // k
            AGG_LOADR(rA, e2);
            AGG_GATHER(vA, rA);
            AGG_FMA8(rB, vB);                  // k+1
            AGG_FMA8(rA, vA);                  // k+2
        } else if (k + 1 < nr) {               // 2 left: rounds k,k+1
            AGG_GATHER(vB, rB);
            AGG_FMA8(rA, vA);                  // k
            AGG_FMA8(rB, vB);                  // k+1
        } else {                               // 1 left: round k
            AGG_FMA8(rA, vA);
        }
    }

    if (n < NN) {
        const size_t idx = (size_t)s * NN * 4 + (size_t)n * 4 + f4;   // uint4 units
        uint4 xv = ((const uint4*)x0s)[idx];
        float z0 = (1.f - ALPHA) * a0 + ALPHA * bf2f((u16)xv.x);
        float z1 = (1.f - ALPHA) * a1 + ALPHA * bf2f((u16)(xv.x >> 16));
        float z2 = (1.f - ALPHA) * a2 + ALPHA * bf2f((u16)xv.y);
        float z3 = (1.f - ALPHA) * a3 + ALPHA * bf2f((u16)(xv.y >> 16));
        float z4 = (1.f - ALPHA) * a4 + ALPHA * bf2f((u16)xv.z);
        float z5 = (1.f - ALPHA) * a5 + ALPHA * bf2f((u16)(xv.z >> 16));
        float z6 = (1.f - ALPHA) * a6 + ALPHA * bf2f((u16)xv.w);
        float z7 = (1.f - ALPHA) * a7 + ALPHA * bf2f((u16)(xv.w >> 16));
        uint4 o;
        o.x = (u32)f2bf(z0) | ((u32)f2bf(z1) << 16);
        o.y = (u32)f2bf(z2) | ((u32)f2bf(z3) << 16);
        o.z = (u32)f2bf(z4) | ((u32)f2bf(z5) << 16);
        o.w = (u32)f2bf(z6) | ((u32)f2bf(z7) << 16);
        ((uint4*)zs)[idx] = o;
    }
}

// ---------------- conv MFMA GEMM: h' = relu(z @ Wfold), slab layout ---------
__global__ __launch_bounds__(256) void k_gemm_conv(const u16* __restrict__ z,
                                                   const u16* __restrict__ Wt,
                                                   u16* __restrict__ hout) {
    const int lane = threadIdx.x & 63;
    const int wave = threadIdx.x >> 6;
    const int q = lane >> 4;
    const int m16 = lane & 15;
    const int node = blockIdx.x * 64 + wave * 16 + m16;
    const int nload = node < NN ? node : NN - 1;

    short8 zf[4];
#pragma unroll
    for (int s = 0; s < 4; ++s)
        zf[s] = *(const short8*)(z + (size_t)s * NN * 32 + (size_t)nload * 32 + q * 8);

    f32x4 acc[8];
#pragma unroll
    for (int c = 0; c < 8; ++c) {
        f32x4 a = {0.f, 0.f, 0.f, 0.f};
        const u16* wp = Wt + (size_t)(c * 16 + m16) * 128 + q * 8;
#pragma unroll
        for (int s = 0; s < 4; ++s) {
            short8 wf = *(const short8*)(wp + s * 32);
            a = __builtin_amdgcn_mfma_f32_16x16x32_bf16(wf, zf[s], a, 0, 0, 0);
        }
        acc[c] = a;
    }

    if (node < NN) {
#pragma unroll
        for (int c = 0; c < 8; ++c) {
            const int f0 = c * 16 + q * 4;
            float v0 = acc[c][0] > 0.f ? acc[c][0] : 0.f;
            float v1 = acc[c][1] > 0.f ? acc[c][1] : 0.f;
            float v2 = acc[c][2] > 0.f ? acc[c][2] : 0.f;
            float v3 = acc[c][3] > 0.f ? acc[c][3] : 0.f;
            ushort4 o;
            o.x = f2bf(v0); o.y = f2bf(v1); o.z = f2bf(v2); o.w = f2bf(v3);
            *(ushort4*)(hout + (size_t)(f0 >> 5) * NN * 32
                        + (size_t)node * 32 + (f0 & 31)) = o;
        }
    }
}

// ---------------- fused last conv + final projection ----------------
__global__ __launch_bounds__(256) void k_gemm_last(const u16* __restrict__ z,
                                                   const u16* __restrict__ wf5,
                                                   const u16* __restrict__ w1t,
                                                   const float* __restrict__ b1,
                                                   float* __restrict__ out) {
    __shared__ __align__(16) u16 hl[4][16][136];   // +8 pad: conflict-free
    const int lane = threadIdx.x & 63;
    const int wave = threadIdx.x >> 6;
    const int q = lane >> 4;
    const int m16 = lane & 15;
    const int node = blockIdx.x * 64 + wave * 16 + m16;
    const int nload = node < NN ? node : NN - 1;

    short8 zf[4];
#pragma unroll
    for (int s = 0; s < 4; ++s)
        zf[s] = *(const short8*)(z + (size_t)s * NN * 32 + (size_t)nload * 32 + q * 8);

    // ---- h = relu(z @ Wfold5), bf16 into LDS
#pragma unroll
    for (int c = 0; c < 8; ++c) {
        f32x4 a = {0.f, 0.f, 0.f, 0.f};
        const u16* wp = wf5 + (size_t)(c * 16 + m16) * 128 + q * 8;
#pragma unroll
        for (int s = 0; s < 4; ++s) {
            short8 wf = *(const short8*)(wp + s * 32);
            a = __builtin_amdgcn_mfma_f32_16x16x32_bf16(wf, zf[s], a, 0, 0, 0);
        }
        float v0 = a[0] > 0.f ? a[0] : 0.f;
        float v1 = a[1] > 0.f ? a[1] : 0.f;
        float v2 = a[2] > 0.f ? a[2] : 0.f;
        float v3 = a[3] > 0.f ? a[3] : 0.f;
        ushort4 o;
        o.x = f2bf(v0); o.y = f2bf(v1); o.z = f2bf(v2); o.w = f2bf(v3);
        *(ushort4*)&hl[wave][m16][c * 16 + q * 4] = o;
    }
    __syncthreads();

    // ---- out = h @ W1 + b1
    short8 hf[4];
#pragma unroll
    for (int s = 0; s < 4; ++s)
        hf[s] = *(const short8*)&hl[wave][m16][s * 32 + q * 8];

#pragma unroll
    for (int c = 0; c < 4; ++c) {
        f32x4 a = {0.f, 0.f, 0.f, 0.f};
        const u16* wp = w1t + (size_t)(c * 16 + m16) * 128 + q * 8;
#pragma unroll
        for (int s = 0; s < 4; ++s) {
            short8 wf = *(const short8*)(wp + s * 32);
            a = __builtin_amdgcn_mfma_f32_16x16x32_bf16(wf, hf[s], a, 0, 0, 0);
        }
        if (node < NN) {
            const int f0 = c * 16 + q * 4;
            float4 bv = *(const float4*)(b1 + f0);
            float4 o;
            o.x = a[0] + bv.x; o.y = a[1] + bv.y;
            o.z = a[2] + bv.z; o.w = a[3] + bv.w;
            *(float4*)(out + (size_t)node * 64 + f0) = o;
        }
    }
}

// ---------------------------------------------------------------------------

extern "C" void kernel_launch(void* const* d_in, const int* in_sizes, int n_in,
                              void* d_out, int out_size, void* d_ws, size_t ws_size,
                              hipStream_t stream) {
    const float* x    = (const float*)d_in[0];
    const int*   esrc = (const int*)d_in[1];
    const int*   edst = (const int*)d_in[2];
    const float* ew   = (const float*)d_in[3];
    const float* W0   = (const float*)d_in[4];
    const float* b0   = (const float*)d_in[5];
    const float* W1   = (const float*)d_in[6];
    const float* b1   = (const float*)d_in[7];
    const float* cw   = (const float*)d_in[8];
    float* out = (float*)d_out;

    // workspace layout; slab buffers are [4][NN][32] bf16
    u32* ep4 = (u32*)d_ws;                         // EPCAP padded edge slots
    u16* x0s = (u16*)(ep4 + EPCAP);
    u16* hb1 = x0s + (size_t)4 * NN * 32;
    u16* hb2 = hb1 + (size_t)4 * NN * 32;
    u16* zsb = hb2 + (size_t)4 * NN * 32;
    u16* w0t = zsb + (size_t)4 * NN * 32;
    u16* wft = w0t + 128 * 128;
    u16* w1t = wft + 6 * 128 * 128;
    int* deg = (int*)(w1t + 64 * 128);
    int* bsum = deg + NN;
    int* offs = bsum + NB;
    int* cur = offs + NN + 1;

    // ---- CSR build + weight prep; bucket merged with layer-0 GEMM
    (void)hipMemsetAsync(ep4, 0, (size_t)EPCAP * sizeof(u32), stream);
    (void)hipMemsetAsync(deg, 0, (size_t)(NN + NB) * sizeof(int), stream);
    k_hist_prep<<<HB + PB, 256, 0, stream>>>(edst, deg, W0, cw, W1, w0t, wft, w1t, EE);
    k_scan_lb<<<NB, 256, 0, stream>>>(deg, bsum, offs, cur);
    k_bucket_g0<<<HB * 8 + GA, 256, 0, stream>>>(esrc, edst, ew, cur, ep4,
                                                 x, w0t, b0, x0s, EE);

    // ---- convs 0..4: z = 0.9*agg(h) + 0.1*x0 ; h' = relu(z @ Wfold)
    const u16* hin = x0s;
    u16* houts[5] = {hb1, hb2, hb1, hb2, hb1};
    for (int i = 0; i < 5; ++i) {
        k_agg_z<<<AGGB, 256, 0, stream>>>(offs, ep4, hin, x0s, zsb);
        k_gemm_conv<<<GA, 256, 0, stream>>>(zsb, wft + (size_t)i * 16384, houts[i]);
        hin = houts[i];
    }

    // ---- conv 5 fused with final projection
    k_agg_z<<<AGGB, 256, 0, stream>>>(offs, ep4, hin, x0s, zsb);
    k_gemm_last<<<GA, 256, 0, stream>>>(zsb, wft + (size_t)5 * 16384, w1t, b1, out);
}

// Round 10
// 469.240 us; speedup vs baseline: 1.0519x; 1.0519x over previous
//
#include <hip/hip_runtime.h>
#include <cstdint>
#include <cstddef>

// ---------------------------------------------------------------------------
// GCN2: h = relu(x@W0+b0); 6x { agg = scatter_sum(w*h[src] -> dst);
//        z = 0.9*agg + 0.1*x0; h = relu(z @ ((1-b)I + b*Wc)) };
//        out = h@W1 + b1
// R0 871 ... R10 504 (XCD-pinned slab agg). R14 502. R16 501.
// R17 533 grid-stride (CLOSED). R18/R19 573 nt (CLOSED). R20 615 fusion
// (CLOSED; slab-L2 locality is THE asset). R21 800 degree sort (CLOSED).
// R22 475 WIN: degree padding x8. R23 468 small WIN: ep-load pipeline.
// R24 475 REGRESSION: single-pass bucket (slice=b&7 IS write-side XCD
// pinning; bucket CLOSED). R25 494 REGRESSION: 2-deep gather ping-pong —
// vA+vB=64 extra VGPR crossed the 128 cliff. In-lane gather pipelining
// VGPR-infeasible; R23 inner loop restored.
// R26 (this): 8 lanes/node split-rounds. Evidence: VALU ~5us + L2 lines
// ~6us vs dispatch ~46us; rounds cost ~2000cy queued; wave serializes
// ~3.3 rounds. Get overlap from WAVE parallelism, not registers: two
// 4-lane sub-groups per node take alternating 8-edge rounds (serial
// rounds ~1.8), blocks 3128->6256, shfl_xor(4) combines halves. Lines/
// VALU/VGPR invariant. FP association changes — already nondeterministic
// via bucket atomic race; tolerance passes.
// Predict agg -20..35% each, total ~390-430. Neutral/regression ->
// revert R23 final; agg at structural limit.
// ---------------------------------------------------------------------------

#define NN 50000
#define EE 800000

constexpr float ALPHA   = 0.1f;
constexpr float BETA_C  = 0.05406722127027574f;   // log(0.5/9 + 1)

constexpr int NB = (NN + 255) / 256;              // 196 scan blocks
constexpr int HB = (EE + 255) / 256;              // 3125 edge chunks
constexpr int PREP_TOT = 128 * 128 + 6 * 128 * 128 + 64 * 128;   // 122880
constexpr int PB = (PREP_TOT + 255) / 256;        // 480 prep blocks
constexpr int SLICE = NN / 8;                     // 6250 dst nodes per slice
constexpr int GA = (NN + 63) / 64;                // 782 gemm blocks
constexpr int AGGB = 8 * 782;                     // 6256 agg blocks (32-node chunks)
constexpr int EPCAP = EE + 7 * NN + 16;           // padded slots + slack

typedef unsigned short u16;
typedef unsigned int   u32;
typedef __attribute__((ext_vector_type(8))) short short8;
typedef __attribute__((ext_vector_type(4))) float f32x4;

__device__ __forceinline__ float bf2f(u16 u) {
    union { float f; u32 i; } c; c.i = ((u32)u) << 16; return c.f;
}
__device__ __forceinline__ u16 f2bf(float f) {          // round-to-nearest-even
    union { float f; u32 i; } c; c.f = f;
    u32 r = c.i + 0x7fffu + ((c.i >> 16) & 1u);
    return (u16)(r >> 16);
}

// ------------- merged: histogram (blocks < HB) + weight prep (rest) ---------
__global__ void k_hist_prep(const int* __restrict__ edst, int* __restrict__ deg,
                            const float* __restrict__ W0, const float* __restrict__ cw,
                            const float* __restrict__ W1, u16* __restrict__ w0t,
                            u16* __restrict__ wft, u16* __restrict__ w1t, int E) {
    int b = blockIdx.x;
    if (b < HB) {
        int i = b * 256 + threadIdx.x;
        if (i < E) atomicAdd(&deg[edst[i]], 1);
    } else {
        int i = (b - HB) * 256 + threadIdx.x;
        if (i < 16384) {
            int n = i >> 7, k = i & 127;
            w0t[i] = f2bf(W0[k * 128 + n]);
        } else if (i < 16384 + 6 * 16384) {
            int r = i - 16384;
            int l = r >> 14; int t = r & 16383;
            int n = t >> 7, k = t & 127;
            float v = BETA_C * cw[l * 16384 + k * 128 + n]
                      + ((k == n) ? (1.f - BETA_C) : 0.f);
            wft[r] = f2bf(v);
        } else if (i < PREP_TOT) {
            int r = i - (16384 + 6 * 16384);
            int n = r >> 7, k = r & 127;
            w1t[r] = f2bf(W1[k * 64 + n]);
        }
    }
}

// ---------------- single-dispatch scan: publish-first parallel lookback -----
// Scans PADDED degrees ((deg+7)&~7); bucket fills real edges, pads zeroed.
__global__ __launch_bounds__(256) void k_scan_lb(const int* __restrict__ deg,
                                                 int* __restrict__ bsum,
                                                 int* __restrict__ offs,
                                                 int* __restrict__ cur) {
    __shared__ int sh[256];
    __shared__ int sw[4];
    const int c = blockIdx.x, tid = threadIdx.x;
    const int i = c * 256 + tid;
    int v = (i < NN) ? ((deg[i] + 7) & ~7) : 0;
    sh[tid] = v;
    __syncthreads();
#pragma unroll
    for (int o = 1; o < 256; o <<= 1) {
        int u = (tid >= o) ? sh[tid - o] : 0;
        __syncthreads();
        sh[tid] += u;
        __syncthreads();
    }
    if (tid == 255) atomicExch(&bsum[c], sh[255] + 1);   // publish (nonzero)
    int part = 0;
    for (int t = tid; t < c; t += 256) {                 // parallel lookback
        int b;
        do { b = atomicAdd(&bsum[t], 0); } while (b == 0);
        part += b - 1;
    }
#pragma unroll
    for (int o = 32; o > 0; o >>= 1) part += __shfl_down(part, o);
    if ((tid & 63) == 0) sw[tid >> 6] = part;
    __syncthreads();
    const int base = sw[0] + sw[1] + sw[2] + sw[3];
    const int ex = base + sh[tid] - v;
    if (i < NN) {
        offs[i] = ex;
        cur[i]  = ex;
        if (i == NN - 1) offs[NN] = ex + v;
    }
}

// ---- layer-0 GEMM tile body (x fp32 row-major -> relu(x@W0+b0) bf16 slab) --
__device__ __forceinline__ void gemm0_tile(int t, const float* __restrict__ x,
                                           const u16* __restrict__ w0t,
                                           const float* __restrict__ b0,
                                           u16* __restrict__ x0s) {
    const int lane = threadIdx.x & 63;
    const int wave = threadIdx.x >> 6;
    const int q = lane >> 4;
    const int m16 = lane & 15;
    const int node = t * 64 + wave * 16 + m16;
    const int nload = node < NN ? node : NN - 1;

    short8 zf[4];
    const float* xp = x + (size_t)nload * 128 + q * 8;
#pragma unroll
    for (int s = 0; s < 4; ++s) {
        float4 u0 = *(const float4*)(xp + s * 32);
        float4 u1 = *(const float4*)(xp + s * 32 + 4);
        short8 z;
        z[0] = (short)f2bf(u0.x); z[1] = (short)f2bf(u0.y);
        z[2] = (short)f2bf(u0.z); z[3] = (short)f2bf(u0.w);
        z[4] = (short)f2bf(u1.x); z[5] = (short)f2bf(u1.y);
        z[6] = (short)f2bf(u1.z); z[7] = (short)f2bf(u1.w);
        zf[s] = z;
    }

    f32x4 acc[8];
#pragma unroll
    for (int c = 0; c < 8; ++c) {
        f32x4 a = {0.f, 0.f, 0.f, 0.f};
        const u16* wp = w0t + (size_t)(c * 16 + m16) * 128 + q * 8;
#pragma unroll
        for (int s = 0; s < 4; ++s) {
            short8 wf = *(const short8*)(wp + s * 32);
            a = __builtin_amdgcn_mfma_f32_16x16x32_bf16(wf, zf[s], a, 0, 0, 0);
        }
        acc[c] = a;
    }

    if (node < NN) {
#pragma unroll
        for (int c = 0; c < 8; ++c) {
            const int f0 = c * 16 + q * 4;
            float4 bv = *(const float4*)(b0 + f0);
            float v0 = acc[c][0] + bv.x; v0 = v0 > 0.f ? v0 : 0.f;
            float v1 = acc[c][1] + bv.y; v1 = v1 > 0.f ? v1 : 0.f;
            float v2 = acc[c][2] + bv.z; v2 = v2 > 0.f ? v2 : 0.f;
            float v3 = acc[c][3] + bv.w; v3 = v3 > 0.f ? v3 : 0.f;
            ushort4 o;
            o.x = f2bf(v0); o.y = f2bf(v1); o.z = f2bf(v2); o.w = f2bf(v3);
            *(ushort4*)(x0s + (size_t)(f0 >> 5) * NN * 32
                        + (size_t)node * 32 + (f0 & 31)) = o;
        }
    }
}

// ------ merged: 8-way dst-sliced bucket scatter + layer-0 GEMM (indep) ------
// slice = b&7 == XCD under round-robin dispatch -> cur/ep writes L2-local.
__global__ __launch_bounds__(256) void k_bucket_g0(const int* __restrict__ src,
                                                   const int* __restrict__ dst,
                                                   const float* __restrict__ w,
                                                   int* __restrict__ cur,
                                                   u32* __restrict__ ep,
                                                   const float* __restrict__ x,
                                                   const u16* __restrict__ w0t,
                                                   const float* __restrict__ b0,
                                                   u16* __restrict__ x0s, int E) {
    const int b = blockIdx.x;
    if (b < HB * 8) {
        const int slice = b & 7;
        const int i = (b >> 3) * 256 + threadIdx.x;
        if (i >= E) return;
        const int d = dst[i];
        const int lo = slice * SLICE;
        if (d >= lo && d < lo + SLICE) {
            int pos = atomicAdd(&cur[d], 1);
            ep[pos] = ((u32)f2bf(w[i]) << 16) | (u32)src[i];
        }
    } else {
        gemm0_tile(b - HB * 8, x, w0t, b0, x0s);
    }
}

// ------- XCD-pinned slab aggregate + z-fold (R26: 8 lanes/node split) -------
// Slab layout F[s][n][32] bf16; slab=(bid&7)>>1 -> XCD pair owns one 3.2MB
// slab (L2-resident). Wave = 8 nodes x 8 lanes: two 4-lane sub-groups per
// node take alternating 8-edge rounds; shfl_xor(4) combines partial sums.
// Ranges exact multiples of 8 (R22 padding; pads w=0 -> +0.0f exact).
__global__ __launch_bounds__(256) void k_agg_z(const int* __restrict__ offs,
                                               const u32* __restrict__ ep,
                                               const u16* __restrict__ hs,
                                               const u16* __restrict__ x0s,
                                               u16* __restrict__ zs) {
    const int bid = blockIdx.x;
    const int s     = (bid & 7) >> 1;
    const int chunk = ((bid >> 3) << 1) | (bid & 1);     // 0..1563
    const int lane = threadIdx.x & 63;
    const int wave = threadIdx.x >> 6;
    const int g   = lane >> 3;         // node group 0..7
    const int sub = (lane >> 2) & 1;   // round-half 0/1
    const int f4  = lane & 3;          // uint4 index within 64B slab row
    const int n  = chunk * 32 + wave * 8 + g;
    const int nc = n < NN ? n : NN - 1;
    const uint4* table = (const uint4*)(hs + (size_t)s * NN * 32);

    const int beg = offs[nc], end = offs[nc + 1];
    float a0 = 0.f, a1 = 0.f, a2 = 0.f, a3 = 0.f;
    float a4 = 0.f, a5 = 0.f, a6 = 0.f, a7 = 0.f;
    for (int e = beg + sub * 8; e + 7 < end; e += 16) {
        u32 r[8]; uint4 v[8];
#pragma unroll
        for (int j = 0; j < 8; ++j) r[j] = ep[e + j];
#pragma unroll
        for (int j = 0; j < 8; ++j)
            v[j] = table[(size_t)(r[j] & 0xffffu) * 4 + f4];
#pragma unroll
        for (int j = 0; j < 8; ++j) {
            float w = bf2f((u16)(r[j] >> 16));
            a0 += w * bf2f((u16)v[j].x);  a1 += w * bf2f((u16)(v[j].x >> 16));
            a2 += w * bf2f((u16)v[j].y);  a3 += w * bf2f((u16)(v[j].y >> 16));
            a4 += w * bf2f((u16)v[j].z);  a5 += w * bf2f((u16)(v[j].z >> 16));
            a6 += w * bf2f((u16)v[j].w);  a7 += w * bf2f((u16)(v[j].w >> 16));
        }
    }
    // combine the two round-halves (partner lane = lane ^ 4: same node, same f4)
    a0 += __shfl_xor(a0, 4);  a1 += __shfl_xor(a1, 4);
    a2 += __shfl_xor(a2, 4);  a3 += __shfl_xor(a3, 4);
    a4 += __shfl_xor(a4, 4);  a5 += __shfl_xor(a5, 4);
    a6 += __shfl_xor(a6, 4);  a7 += __shfl_xor(a7, 4);

    if (n < NN && sub == 0) {
        const size_t idx = (size_t)s * NN * 4 + (size_t)n * 4 + f4;   // uint4 units
        uint4 xv = ((const uint4*)x0s)[idx];
        float z0 = (1.f - ALPHA) * a0 + ALPHA * bf2f((u16)xv.x);
        float z1 = (1.f - ALPHA) * a1 + ALPHA * bf2f((u16)(xv.x >> 16));
        float z2 = (1.f - ALPHA) * a2 + ALPHA * bf2f((u16)xv.y);
        float z3 = (1.f - ALPHA) * a3 + ALPHA * bf2f((u16)(xv.y >> 16));
        float z4 = (1.f - ALPHA) * a4 + ALPHA * bf2f((u16)xv.z);
        float z5 = (1.f - ALPHA) * a5 + ALPHA * bf2f((u16)(xv.z >> 16));
        float z6 = (1.f - ALPHA) * a6 + ALPHA * bf2f((u16)xv.w);
        float z7 = (1.f - ALPHA) * a7 + ALPHA * bf2f((u16)(xv.w >> 16));
        uint4 o;
        o.x = (u32)f2bf(z0) | ((u32)f2bf(z1) << 16);
        o.y = (u32)f2bf(z2) | ((u32)f2bf(z3) << 16);
        o.z = (u32)f2bf(z4) | ((u32)f2bf(z5) << 16);
        o.w = (u32)f2bf(z6) | ((u32)f2bf(z7) << 16);
        ((uint4*)zs)[idx] = o;
    }
}

// ---------------- conv MFMA GEMM: h' = relu(z @ Wfold), slab layout ---------
__global__ __launch_bounds__(256) void k_gemm_conv(const u16* __restrict__ z,
                                                   const u16* __restrict__ Wt,
                                                   u16* __restrict__ hout) {
    const int lane = threadIdx.x & 63;
    const int wave = threadIdx.x >> 6;
    const int q = lane >> 4;
    const int m16 = lane & 15;
    const int node = blockIdx.x * 64 + wave * 16 + m16;
    const int nload = node < NN ? node : NN - 1;

    short8 zf[4];
#pragma unroll
    for (int s = 0; s < 4; ++s)
        zf[s] = *(const short8*)(z + (size_t)s * NN * 32 + (size_t)nload * 32 + q * 8);

    f32x4 acc[8];
#pragma unroll
    for (int c = 0; c < 8; ++c) {
        f32x4 a = {0.f, 0.f, 0.f, 0.f};
        const u16* wp = Wt + (size_t)(c * 16 + m16) * 128 + q * 8;
#pragma unroll
        for (int s = 0; s < 4; ++s) {
            short8 wf = *(const short8*)(wp + s * 32);
            a = __builtin_amdgcn_mfma_f32_16x16x32_bf16(wf, zf[s], a, 0, 0, 0);
        }
        acc[c] = a;
    }

    if (node < NN) {
#pragma unroll
        for (int c = 0; c < 8; ++c) {
            const int f0 = c * 16 + q * 4;
            float v0 = acc[c][0] > 0.f ? acc[c][0] : 0.f;
            float v1 = acc[c][1] > 0.f ? acc[c][1] : 0.f;
            float v2 = acc[c][2] > 0.f ? acc[c][2] : 0.f;
            float v3 = acc[c][3] > 0.f ? acc[c][3] : 0.f;
            ushort4 o;
            o.x = f2bf(v0); o.y = f2bf(v1); o.z = f2bf(v2); o.w = f2bf(v3);
            *(ushort4*)(hout + (size_t)(f0 >> 5) * NN * 32
                        + (size_t)node * 32 + (f0 & 31)) = o;
        }
    }
}

// ---------------- fused last conv + final projection ----------------
__global__ __launch_bounds__(256) void k_gemm_last(const u16* __restrict__ z,
                                                   const u16* __restrict__ wf5,
                                                   const u16* __restrict__ w1t,
                                                   const float* __restrict__ b1,
                                                   float* __restrict__ out) {
    __shared__ __align__(16) u16 hl[4][16][136];   // +8 pad: conflict-free
    const int lane = threadIdx.x & 63;
    const int wave = threadIdx.x >> 6;
    const int q = lane >> 4;
    const int m16 = lane & 15;
    const int node = blockIdx.x * 64 + wave * 16 + m16;
    const int nload = node < NN ? node : NN - 1;

    short8 zf[4];
#pragma unroll
    for (int s = 0; s < 4; ++s)
        zf[s] = *(const short8*)(z + (size_t)s * NN * 32 + (size_t)nload * 32 + q * 8);

    // ---- h = relu(z @ Wfold5), bf16 into LDS
#pragma unroll
    for (int c = 0; c < 8; ++c) {
        f32x4 a = {0.f, 0.f, 0.f, 0.f};
        const u16* wp = wf5 + (size_t)(c * 16 + m16) * 128 + q * 8;
#pragma unroll
        for (int s = 0; s < 4; ++s) {
            short8 wf = *(const short8*)(wp + s * 32);
            a = __builtin_amdgcn_mfma_f32_16x16x32_bf16(wf, zf[s], a, 0, 0, 0);
        }
        float v0 = a[0] > 0.f ? a[0] : 0.f;
        float v1 = a[1] > 0.f ? a[1] : 0.f;
        float v2 = a[2] > 0.f ? a[2] : 0.f;
        float v3 = a[3] > 0.f ? a[3] : 0.f;
        ushort4 o;
        o.x = f2bf(v0); o.y = f2bf(v1); o.z = f2bf(v2); o.w = f2bf(v3);
        *(ushort4*)&hl[wave][m16][c * 16 + q * 4] = o;
    }
    __syncthreads();

    // ---- out = h @ W1 + b1
    short8 hf[4];
#pragma unroll
    for (int s = 0; s < 4; ++s)
        hf[s] = *(const short8*)&hl[wave][m16][s * 32 + q * 8];

#pragma unroll
    for (int c = 0; c < 4; ++c) {
        f32x4 a = {0.f, 0.f, 0.f, 0.f};
        const u16* wp = w1t + (size_t)(c * 16 + m16) * 128 + q * 8;
#pragma unroll
        for (int s = 0; s < 4; ++s) {
            short8 wf = *(const short8*)(wp + s * 32);
            a = __builtin_amdgcn_mfma_f32_16x16x32_bf16(wf, hf[s], a, 0, 0, 0);
        }
        if (node < NN) {
            const int f0 = c * 16 + q * 4;
            float4 bv = *(const float4*)(b1 + f0);
            float4 o;
            o.x = a[0] + bv.x; o.y = a[1] + bv.y;
            o.z = a[2] + bv.z; o.w = a[3] + bv.w;
            *(float4*)(out + (size_t)node * 64 + f0) = o;
        }
    }
}

// ---------------------------------------------------------------------------

extern "C" void kernel_launch(void* const* d_in, const int* in_sizes, int n_in,
                              void* d_out, int out_size, void* d_ws, size_t ws_size,
                              hipStream_t stream) {
    const float* x    = (const float*)d_in[0];
    const int*   esrc = (const int*)d_in[1];
    const int*   edst = (const int*)d_in[2];
    const float* ew   = (const float*)d_in[3];
    const float* W0   = (const float*)d_in[4];
    const float* b0   = (const float*)d_in[5];
    const float* W1   = (const float*)d_in[6];
    const float* b1   = (const float*)d_in[7];
    const float* cw   = (const float*)d_in[8];
    float* out = (float*)d_out;

    // workspace layout; slab buffers are [4][NN][32] bf16
    u32* ep4 = (u32*)d_ws;                         // EPCAP padded edge slots
    u16* x0s = (u16*)(ep4 + EPCAP);
    u16* hb1 = x0s + (size_t)4 * NN * 32;
    u16* hb2 = hb1 + (size_t)4 * NN * 32;
    u16* zsb = hb2 + (size_t)4 * NN * 32;
    u16* w0t = zsb + (size_t)4 * NN * 32;
    u16* wft = w0t + 128 * 128;
    u16* w1t = wft + 6 * 128 * 128;
    int* deg = (int*)(w1t + 64 * 128);
    int* bsum = deg + NN;
    int* offs = bsum + NB;
    int* cur = offs + NN + 1;

    // ---- CSR build + weight prep; bucket merged with layer-0 GEMM
    (void)hipMemsetAsync(ep4, 0, (size_t)EPCAP * sizeof(u32), stream);
    (void)hipMemsetAsync(deg, 0, (size_t)(NN + NB) * sizeof(int), stream);
    k_hist_prep<<<HB + PB, 256, 0, stream>>>(edst, deg, W0, cw, W1, w0t, wft, w1t, EE);
    k_scan_lb<<<NB, 256, 0, stream>>>(deg, bsum, offs, cur);
    k_bucket_g0<<<HB * 8 + GA, 256, 0, stream>>>(esrc, edst, ew, cur, ep4,
                                                 x, w0t, b0, x0s, EE);

    // ---- convs 0..4: z = 0.9*agg(h) + 0.1*x0 ; h' = relu(z @ Wfold)
    const u16* hin = x0s;
    u16* houts[5] = {hb1, hb2, hb1, hb2, hb1};
    for (int i = 0; i < 5; ++i) {
        k_agg_z<<<AGGB, 256, 0, stream>>>(offs, ep4, hin, x0s, zsb);
        k_gemm_conv<<<GA, 256, 0, stream>>>(zsb, wft + (size_t)i * 16384, houts[i]);
        hin = houts[i];
    }

    // ---- conv 5 fused with final projection
    k_agg_z<<<AGGB, 256, 0, stream>>>(offs, ep4, hin, x0s, zsb);
    k_gemm_last<<<GA, 256, 0, stream>>>(zsb, wft + (size_t)5 * 16384, w1t, b1, out);
}

// Round 11
// 467.518 us; speedup vs baseline: 1.0558x; 1.0037x over previous
//
#include <hip/hip_runtime.h>
#include <cstdint>
#include <cstddef>

// ---------------------------------------------------------------------------
// GCN2: h = relu(x@W0+b0); 6x { agg = scatter_sum(w*h[src] -> dst);
//        z = 0.9*agg + 0.1*x0; h = relu(z @ ((1-b)I + b*Wc)) };
//        out = h@W1 + b1
// R0 871 ... R10 504 (XCD-pinned slab agg). R14 502. R16 501.
// R17 533 grid-stride (CLOSED). R18/R19 573 nt (CLOSED). R20 615 fusion
// (CLOSED; slab-L2 locality is THE asset). R21 800 degree sort (CLOSED).
// R22 475 WIN: degree padding x8. R23 468 small WIN: ep-load pipeline.
// R24 475 REGRESSION: single-pass bucket — slice=b&7 IS write-side XCD
// pinning (92us unsliced vs 62 sliced; bucket CLOSED).
// R25 494 REGRESSION: 2-deep gather ping-pong (VGPR cliff).
// R26 469 NEUTRAL: 8-lanes/node split rounds — agg time invariant to
// scheduling shape => bound by divergent-gather (16 lines/wave-instr)
// TA/L1 throughput. Agg inner structure FROZEN at R23 form permanently.
// R27 (this): R23 verbatim + 8-way dst-sliced HISTOGRAM (the last
// unsliced atomic phase; R24 measured the same pattern's penalty).
// 8x dst reads (+22MB streaming) buys XCD-local deg atomics.
// Predict hist -8..12us, total ~456-462. Neutral => declare structural
// limit next round.
// ---------------------------------------------------------------------------

#define NN 50000
#define EE 800000

constexpr float ALPHA   = 0.1f;
constexpr float BETA_C  = 0.05406722127027574f;   // log(0.5/9 + 1)

constexpr int NB = (NN + 255) / 256;              // 196 scan blocks
constexpr int HB = (EE + 255) / 256;              // 3125 edge chunks
constexpr int PREP_TOT = 128 * 128 + 6 * 128 * 128 + 64 * 128;   // 122880
constexpr int PB = (PREP_TOT + 255) / 256;        // 480 prep blocks
constexpr int SLICE = NN / 8;                     // 6250 dst nodes per slice
constexpr int GA = (NN + 63) / 64;                // 782 gemm blocks / slab chunks
constexpr int AGGB = 8 * ((GA + 1) / 2);          // 3128 agg blocks (XCD-pinned)
constexpr int EPCAP = EE + 7 * NN + 16;           // padded edge slots + slack

typedef unsigned short u16;
typedef unsigned int   u32;
typedef __attribute__((ext_vector_type(8))) short short8;
typedef __attribute__((ext_vector_type(4))) float f32x4;

__device__ __forceinline__ float bf2f(u16 u) {
    union { float f; u32 i; } c; c.i = ((u32)u) << 16; return c.f;
}
__device__ __forceinline__ u16 f2bf(float f) {          // round-to-nearest-even
    union { float f; u32 i; } c; c.f = f;
    u32 r = c.i + 0x7fffu + ((c.i >> 16) & 1u);
    return (u16)(r >> 16);
}

// ---- merged: 8-way dst-sliced histogram (blocks < HB*8) + weight prep -----
// slice = b&7 == XCD under round-robin dispatch -> deg atomics L2-local
// (R24-measured pattern: sliced atomics 62us vs unsliced 92us for bucket).
__global__ void k_hist_prep(const int* __restrict__ edst, int* __restrict__ deg,
                            const float* __restrict__ W0, const float* __restrict__ cw,
                            const float* __restrict__ W1, u16* __restrict__ w0t,
                            u16* __restrict__ wft, u16* __restrict__ w1t, int E) {
    int b = blockIdx.x;
    if (b < HB * 8) {
        const int slice = b & 7;
        const int i = (b >> 3) * 256 + threadIdx.x;
        if (i >= E) return;
        const int d = edst[i];
        const int lo = slice * SLICE;
        if (d >= lo && d < lo + SLICE) atomicAdd(&deg[d], 1);
    } else {
        int i = (b - HB * 8) * 256 + threadIdx.x;
        if (i < 16384) {
            int n = i >> 7, k = i & 127;
            w0t[i] = f2bf(W0[k * 128 + n]);
        } else if (i < 16384 + 6 * 16384) {
            int r = i - 16384;
            int l = r >> 14; int t = r & 16383;
            int n = t >> 7, k = t & 127;
            float v = BETA_C * cw[l * 16384 + k * 128 + n]
                      + ((k == n) ? (1.f - BETA_C) : 0.f);
            wft[r] = f2bf(v);
        } else if (i < PREP_TOT) {
            int r = i - (16384 + 6 * 16384);
            int n = r >> 7, k = r & 127;
            w1t[r] = f2bf(W1[k * 64 + n]);
        }
    }
}

// ---------------- single-dispatch scan: publish-first parallel lookback -----
// Scans PADDED degrees ((deg+7)&~7); bucket fills real edges, pads zeroed.
__global__ __launch_bounds__(256) void k_scan_lb(const int* __restrict__ deg,
                                                 int* __restrict__ bsum,
                                                 int* __restrict__ offs,
                                                 int* __restrict__ cur) {
    __shared__ int sh[256];
    __shared__ int sw[4];
    const int c = blockIdx.x, tid = threadIdx.x;
    const int i = c * 256 + tid;
    int v = (i < NN) ? ((deg[i] + 7) & ~7) : 0;
    sh[tid] = v;
    __syncthreads();
#pragma unroll
    for (int o = 1; o < 256; o <<= 1) {
        int u = (tid >= o) ? sh[tid - o] : 0;
        __syncthreads();
        sh[tid] += u;
        __syncthreads();
    }
    if (tid == 255) atomicExch(&bsum[c], sh[255] + 1);   // publish (nonzero)
    int part = 0;
    for (int t = tid; t < c; t += 256) {                 // parallel lookback
        int b;
        do { b = atomicAdd(&bsum[t], 0); } while (b == 0);
        part += b - 1;
    }
#pragma unroll
    for (int o = 32; o > 0; o >>= 1) part += __shfl_down(part, o);
    if ((tid & 63) == 0) sw[tid >> 6] = part;
    __syncthreads();
    const int base = sw[0] + sw[1] + sw[2] + sw[3];
    const int ex = base + sh[tid] - v;
    if (i < NN) {
        offs[i] = ex;
        cur[i]  = ex;
        if (i == NN - 1) offs[NN] = ex + v;
    }
}

// ---- layer-0 GEMM tile body (x fp32 row-major -> relu(x@W0+b0) bf16 slab) --
__device__ __forceinline__ void gemm0_tile(int t, const float* __restrict__ x,
                                           const u16* __restrict__ w0t,
                                           const float* __restrict__ b0,
                                           u16* __restrict__ x0s) {
    const int lane = threadIdx.x & 63;
    const int wave = threadIdx.x >> 6;
    const int q = lane >> 4;
    const int m16 = lane & 15;
    const int node = t * 64 + wave * 16 + m16;
    const int nload = node < NN ? node : NN - 1;

    short8 zf[4];
    const float* xp = x + (size_t)nload * 128 + q * 8;
#pragma unroll
    for (int s = 0; s < 4; ++s) {
        float4 u0 = *(const float4*)(xp + s * 32);
        float4 u1 = *(const float4*)(xp + s * 32 + 4);
        short8 z;
        z[0] = (short)f2bf(u0.x); z[1] = (short)f2bf(u0.y);
        z[2] = (short)f2bf(u0.z); z[3] = (short)f2bf(u0.w);
        z[4] = (short)f2bf(u1.x); z[5] = (short)f2bf(u1.y);
        z[6] = (short)f2bf(u1.z); z[7] = (short)f2bf(u1.w);
        zf[s] = z;
    }

    f32x4 acc[8];
#pragma unroll
    for (int c = 0; c < 8; ++c) {
        f32x4 a = {0.f, 0.f, 0.f, 0.f};
        const u16* wp = w0t + (size_t)(c * 16 + m16) * 128 + q * 8;
#pragma unroll
        for (int s = 0; s < 4; ++s) {
            short8 wf = *(const short8*)(wp + s * 32);
            a = __builtin_amdgcn_mfma_f32_16x16x32_bf16(wf, zf[s], a, 0, 0, 0);
        }
        acc[c] = a;
    }

    if (node < NN) {
#pragma unroll
        for (int c = 0; c < 8; ++c) {
            const int f0 = c * 16 + q * 4;
            float4 bv = *(const float4*)(b0 + f0);
            float v0 = acc[c][0] + bv.x; v0 = v0 > 0.f ? v0 : 0.f;
            float v1 = acc[c][1] + bv.y; v1 = v1 > 0.f ? v1 : 0.f;
            float v2 = acc[c][2] + bv.z; v2 = v2 > 0.f ? v2 : 0.f;
            float v3 = acc[c][3] + bv.w; v3 = v3 > 0.f ? v3 : 0.f;
            ushort4 o;
            o.x = f2bf(v0); o.y = f2bf(v1); o.z = f2bf(v2); o.w = f2bf(v3);
            *(ushort4*)(x0s + (size_t)(f0 >> 5) * NN * 32
                        + (size_t)node * 32 + (f0 & 31)) = o;
        }
    }
}

// ------ merged: 8-way dst-sliced bucket scatter + layer-0 GEMM (indep) ------
// slice = b&7 == XCD under round-robin dispatch -> cur/ep writes L2-local.
__global__ __launch_bounds__(256) void k_bucket_g0(const int* __restrict__ src,
                                                   const int* __restrict__ dst,
                                                   const float* __restrict__ w,
                                                   int* __restrict__ cur,
                                                   u32* __restrict__ ep,
                                                   const float* __restrict__ x,
                                                   const u16* __restrict__ w0t,
                                                   const float* __restrict__ b0,
                                                   u16* __restrict__ x0s, int E) {
    const int b = blockIdx.x;
    if (b < HB * 8) {
        const int slice = b & 7;
        const int i = (b >> 3) * 256 + threadIdx.x;
        if (i >= E) return;
        const int d = dst[i];
        const int lo = slice * SLICE;
        if (d >= lo && d < lo + SLICE) {
            int pos = atomicAdd(&cur[d], 1);
            ep[pos] = ((u32)f2bf(w[i]) << 16) | (u32)src[i];
        }
    } else {
        gemm0_tile(b - HB * 8, x, w0t, b0, x0s);
    }
}

// ------- XCD-pinned slab aggregate + z-fold (R23 form — FROZEN) -------------
// Slab layout F[s][n][32] bf16; slab=(bid&7)>>1 -> XCD pair owns one 3.2MB
// slab (L2-resident). Wave = 16 consecutive nodes x 4 lanes (uint4 row part).
// Ranges exact multiples of 8 (R22 padding; pads w=0 -> +0.0f exact).
// Round k+1's ep loads issue before round k's gathers retire.
#define AGG_FMA8()                                                            \
    _Pragma("unroll")                                                         \
    for (int j = 0; j < 8; ++j) {                                             \
        float w = bf2f((u16)(r[j] >> 16));                                    \
        a0 += w * bf2f((u16)v[j].x);  a1 += w * bf2f((u16)(v[j].x >> 16));    \
        a2 += w * bf2f((u16)v[j].y);  a3 += w * bf2f((u16)(v[j].y >> 16));    \
        a4 += w * bf2f((u16)v[j].z);  a5 += w * bf2f((u16)(v[j].z >> 16));    \
        a6 += w * bf2f((u16)v[j].w);  a7 += w * bf2f((u16)(v[j].w >> 16));    \
    }

__global__ __launch_bounds__(256) void k_agg_z(const int* __restrict__ offs,
                                               const u32* __restrict__ ep,
                                               const u16* __restrict__ hs,
                                               const u16* __restrict__ x0s,
                                               u16* __restrict__ zs) {
    const int bid = blockIdx.x;
    const int s     = (bid & 7) >> 1;
    const int chunk = ((bid >> 3) << 1) | (bid & 1);     // 0..781
    const int lane = threadIdx.x & 63;
    const int wave = threadIdx.x >> 6;
    const int g  = lane >> 2;          // node group 0..15
    const int f4 = lane & 3;           // uint4 index within 64B slab row
    const int n  = chunk * 64 + wave * 16 + g;
    const int nc = n < NN ? n : NN - 1;
    const uint4* table = (const uint4*)(hs + (size_t)s * NN * 32);

    const int beg = offs[nc], end = offs[nc + 1];
    float a0 = 0.f, a1 = 0.f, a2 = 0.f, a3 = 0.f;
    float a4 = 0.f, a5 = 0.f, a6 = 0.f, a7 = 0.f;
    int e = beg;
    if (e + 7 < end) {
        u32 r[8];
#pragma unroll
        for (int j = 0; j < 8; ++j) r[j] = ep[e + j];
        e += 8;
        for (; e + 7 < end; e += 8) {
            u32 rn[8];
#pragma unroll
            for (int j = 0; j < 8; ++j) rn[j] = ep[e + j];   // prefetch round k+1
            uint4 v[8];
#pragma unroll
            for (int j = 0; j < 8; ++j)
                v[j] = table[(size_t)(r[j] & 0xffffu) * 4 + f4];
            AGG_FMA8();
#pragma unroll
            for (int j = 0; j < 8; ++j) r[j] = rn[j];
        }
        {   // epilogue: last prefetched group
            uint4 v[8];
#pragma unroll
            for (int j = 0; j < 8; ++j)
                v[j] = table[(size_t)(r[j] & 0xffffu) * 4 + f4];
            AGG_FMA8();
        }
    }
    for (; e < end; ++e) {             // correctness net (0 iters with padding)
        u32 r = ep[e];
        uint4 v = table[(size_t)(r & 0xffffu) * 4 + f4];
        float w = bf2f((u16)(r >> 16));
        a0 += w * bf2f((u16)v.x);  a1 += w * bf2f((u16)(v.x >> 16));
        a2 += w * bf2f((u16)v.y);  a3 += w * bf2f((u16)(v.y >> 16));
        a4 += w * bf2f((u16)v.z);  a5 += w * bf2f((u16)(v.z >> 16));
        a6 += w * bf2f((u16)v.w);  a7 += w * bf2f((u16)(v.w >> 16));
    }
    if (n < NN) {
        const size_t idx = (size_t)s * NN * 4 + (size_t)n * 4 + f4;   // uint4 units
        uint4 xv = ((const uint4*)x0s)[idx];
        float z0 = (1.f - ALPHA) * a0 + ALPHA * bf2f((u16)xv.x);
        float z1 = (1.f - ALPHA) * a1 + ALPHA * bf2f((u16)(xv.x >> 16));
        float z2 = (1.f - ALPHA) * a2 + ALPHA * bf2f((u16)xv.y);
        float z3 = (1.f - ALPHA) * a3 + ALPHA * bf2f((u16)(xv.y >> 16));
        float z4 = (1.f - ALPHA) * a4 + ALPHA * bf2f((u16)xv.z);
        float z5 = (1.f - ALPHA) * a5 + ALPHA * bf2f((u16)(xv.z >> 16));
        float z6 = (1.f - ALPHA) * a6 + ALPHA * bf2f((u16)xv.w);
        float z7 = (1.f - ALPHA) * a7 + ALPHA * bf2f((u16)(xv.w >> 16));
        uint4 o;
        o.x = (u32)f2bf(z0) | ((u32)f2bf(z1) << 16);
        o.y = (u32)f2bf(z2) | ((u32)f2bf(z3) << 16);
        o.z = (u32)f2bf(z4) | ((u32)f2bf(z5) << 16);
        o.w = (u32)f2bf(z6) | ((u32)f2bf(z7) << 16);
        ((uint4*)zs)[idx] = o;
    }
}

// ---------------- conv MFMA GEMM: h' = relu(z @ Wfold), slab layout ---------
__global__ __launch_bounds__(256) void k_gemm_conv(const u16* __restrict__ z,
                                                   const u16* __restrict__ Wt,
                                                   u16* __restrict__ hout) {
    const int lane = threadIdx.x & 63;
    const int wave = threadIdx.x >> 6;
    const int q = lane >> 4;
    const int m16 = lane & 15;
    const int node = blockIdx.x * 64 + wave * 16 + m16;
    const int nload = node < NN ? node : NN - 1;

    short8 zf[4];
#pragma unroll
    for (int s = 0; s < 4; ++s)
        zf[s] = *(const short8*)(z + (size_t)s * NN * 32 + (size_t)nload * 32 + q * 8);

    f32x4 acc[8];
#pragma unroll
    for (int c = 0; c < 8; ++c) {
        f32x4 a = {0.f, 0.f, 0.f, 0.f};
        const u16* wp = Wt + (size_t)(c * 16 + m16) * 128 + q * 8;
#pragma unroll
        for (int s = 0; s < 4; ++s) {
            short8 wf = *(const short8*)(wp + s * 32);
            a = __builtin_amdgcn_mfma_f32_16x16x32_bf16(wf, zf[s], a, 0, 0, 0);
        }
        acc[c] = a;
    }

    if (node < NN) {
#pragma unroll
        for (int c = 0; c < 8; ++c) {
            const int f0 = c * 16 + q * 4;
            float v0 = acc[c][0] > 0.f ? acc[c][0] : 0.f;
            float v1 = acc[c][1] > 0.f ? acc[c][1] : 0.f;
            float v2 = acc[c][2] > 0.f ? acc[c][2] : 0.f;
            float v3 = acc[c][3] > 0.f ? acc[c][3] : 0.f;
            ushort4 o;
            o.x = f2bf(v0); o.y = f2bf(v1); o.z = f2bf(v2); o.w = f2bf(v3);
            *(ushort4*)(hout + (size_t)(f0 >> 5) * NN * 32
                        + (size_t)node * 32 + (f0 & 31)) = o;
        }
    }
}

// ---------------- fused last conv + final projection ----------------
__global__ __launch_bounds__(256) void k_gemm_last(const u16* __restrict__ z,
                                                   const u16* __restrict__ wf5,
                                                   const u16* __restrict__ w1t,
                                                   const float* __restrict__ b1,
                                                   float* __restrict__ out) {
    __shared__ __align__(16) u16 hl[4][16][136];   // +8 pad: conflict-free
    const int lane = threadIdx.x & 63;
    const int wave = threadIdx.x >> 6;
    const int q = lane >> 4;
    const int m16 = lane & 15;
    const int node = blockIdx.x * 64 + wave * 16 + m16;
    const int nload = node < NN ? node : NN - 1;

    short8 zf[4];
#pragma unroll
    for (int s = 0; s < 4; ++s)
        zf[s] = *(const short8*)(z + (size_t)s * NN * 32 + (size_t)nload * 32 + q * 8);

    // ---- h = relu(z @ Wfold5), bf16 into LDS
#pragma unroll
    for (int c = 0; c < 8; ++c) {
        f32x4 a = {0.f, 0.f, 0.f, 0.f};
        const u16* wp = wf5 + (size_t)(c * 16 + m16) * 128 + q * 8;
#pragma unroll
        for (int s = 0; s < 4; ++s) {
            short8 wf = *(const short8*)(wp + s * 32);
            a = __builtin_amdgcn_mfma_f32_16x16x32_bf16(wf, zf[s], a, 0, 0, 0);
        }
        float v0 = a[0] > 0.f ? a[0] : 0.f;
        float v1 = a[1] > 0.f ? a[1] : 0.f;
        float v2 = a[2] > 0.f ? a[2] : 0.f;
        float v3 = a[3] > 0.f ? a[3] : 0.f;
        ushort4 o;
        o.x = f2bf(v0); o.y = f2bf(v1); o.z = f2bf(v2); o.w = f2bf(v3);
        *(ushort4*)&hl[wave][m16][c * 16 + q * 4] = o;
    }
    __syncthreads();

    // ---- out = h @ W1 + b1
    short8 hf[4];
#pragma unroll
    for (int s = 0; s < 4; ++s)
        hf[s] = *(const short8*)&hl[wave][m16][s * 32 + q * 8];

#pragma unroll
    for (int c = 0; c < 4; ++c) {
        f32x4 a = {0.f, 0.f, 0.f, 0.f};
        const u16* wp = w1t + (size_t)(c * 16 + m16) * 128 + q * 8;
#pragma unroll
        for (int s = 0; s < 4; ++s) {
            short8 wf = *(const short8*)(wp + s * 32);
            a = __builtin_amdgcn_mfma_f32_16x16x32_bf16(wf, hf[s], a, 0, 0, 0);
        }
        if (node < NN) {
            const int f0 = c * 16 + q * 4;
            float4 bv = *(const float4*)(b1 + f0);
            float4 o;
            o.x = a[0] + bv.x; o.y = a[1] + bv.y;
            o.z = a[2] + bv.z; o.w = a[3] + bv.w;
            *(float4*)(out + (size_t)node * 64 + f0) = o;
        }
    }
}

// ---------------------------------------------------------------------------

extern "C" void kernel_launch(void* const* d_in, const int* in_sizes, int n_in,
                              void* d_out, int out_size, void* d_ws, size_t ws_size,
                              hipStream_t stream) {
    const float* x    = (const float*)d_in[0];
    const int*   esrc = (const int*)d_in[1];
    const int*   edst = (const int*)d_in[2];
    const float* ew   = (const float*)d_in[3];
    const float* W0   = (const float*)d_in[4];
    const float* b0   = (const float*)d_in[5];
    const float* W1   = (const float*)d_in[6];
    const float* b1   = (const float*)d_in[7];
    const float* cw   = (const float*)d_in[8];
    float* out = (float*)d_out;

    // workspace layout; slab buffers are [4][NN][32] bf16
    u32* ep4 = (u32*)d_ws;                         // EPCAP padded edge slots
    u16* x0s = (u16*)(ep4 + EPCAP);
    u16* hb1 = x0s + (size_t)4 * NN * 32;
    u16* hb2 = hb1 + (size_t)4 * NN * 32;
    u16* zsb = hb2 + (size_t)4 * NN * 32;
    u16* w0t = zsb + (size_t)4 * NN * 32;
    u16* wft = w0t + 128 * 128;
    u16* w1t = wft + 6 * 128 * 128;
    int* deg = (int*)(w1t + 64 * 128);
    int* bsum = deg + NN;
    int* offs = bsum + NB;
    int* cur = offs + NN + 1;

    // ---- CSR build + weight prep; bucket merged with layer-0 GEMM
    (void)hipMemsetAsync(ep4, 0, (size_t)EPCAP * sizeof(u32), stream);
    (void)hipMemsetAsync(deg, 0, (size_t)(NN + NB) * sizeof(int), stream);
    k_hist_prep<<<HB * 8 + PB, 256, 0, stream>>>(edst, deg, W0, cw, W1, w0t, wft, w1t, EE);
    k_scan_lb<<<NB, 256, 0, stream>>>(deg, bsum, offs, cur);
    k_bucket_g0<<<HB * 8 + GA, 256, 0, stream>>>(esrc, edst, ew, cur, ep4,
                                                 x, w0t, b0, x0s, EE);

    // ---- convs 0..4: z = 0.9*agg(h) + 0.1*x0 ; h' = relu(z @ Wfold)
    const u16* hin = x0s;
    u16* houts[5] = {hb1, hb2, hb1, hb2, hb1};
    for (int i = 0; i < 5; ++i) {
        k_agg_z<<<AGGB, 256, 0, stream>>>(offs, ep4, hin, x0s, zsb);
        k_gemm_conv<<<GA, 256, 0, stream>>>(zsb, wft + (size_t)i * 16384, houts[i]);
        hin = houts[i];
    }

    // ---- conv 5 fused with final projection
    k_agg_z<<<AGGB, 256, 0, stream>>>(offs, ep4, hin, x0s, zsb);
    k_gemm_last<<<GA, 256, 0, stream>>>(zsb, wft + (size_t)5 * 16384, w1t, b1, out);
}

// Round 13
// 466.404 us; speedup vs baseline: 1.0583x; 1.0024x over previous
//
#include <hip/hip_runtime.h>
#include <cstdint>
#include <cstddef>

// ---------------------------------------------------------------------------
// GCN2: h = relu(x@W0+b0); 6x { agg = scatter_sum(w*h[src] -> dst);
//        z = 0.9*agg + 0.1*x0; h = relu(z @ ((1-b)I + b*Wc)) };
//        out = h@W1 + b1
// R0 871 ... R10 504 (XCD-pinned slab agg). R14 502. R16 501.
// R17 533 grid-stride (CLOSED). R18/R19 573 nt (CLOSED). R20 615 fusion
// (CLOSED; slab-L2 locality is THE asset). R21 800 degree sort (CLOSED).
// R22 475 WIN: degree padding x8. R23 468 small WIN: ep-load pipeline.
// R24 475 REGRESSION: single-pass bucket (slice=b&7 IS write-side XCD
// pinning; bucket CLOSED). R25 494 REGRESSION: gather ping-pong (VGPR
// cliff). R26 469 NEUTRAL: split-rounds — agg scheduling-invariant; agg
// FROZEN at R23 form. R27 467.5 neutral: sliced histogram (kept).
// R28: dispatch-overhead trim. ep memset (3.4MB serial + 1 launch)
// exists only to zero R22's pad slots; zero them INSIDE bucket instead:
// third block range (NB blocks), thread i zeroes [offs[i]+deg[i],
// offs[i+1]) — disjoint from atomic fills, race-free. 16->15 dispatches.
// Predict total ~460-464; bucket unchanged. If null: launch/memset
// overhead negligible -> all phases at evidence-backed floor -> declare
// structural limit next round.
// R29 = R28 resubmitted verbatim (container infra failure, never measured).
// ---------------------------------------------------------------------------

#define NN 50000
#define EE 800000

constexpr float ALPHA   = 0.1f;
constexpr float BETA_C  = 0.05406722127027574f;   // log(0.5/9 + 1)

constexpr int NB = (NN + 255) / 256;              // 196 scan blocks
constexpr int HB = (EE + 255) / 256;              // 3125 edge chunks
constexpr int PREP_TOT = 128 * 128 + 6 * 128 * 128 + 64 * 128;   // 122880
constexpr int PB = (PREP_TOT + 255) / 256;        // 480 prep blocks
constexpr int SLICE = NN / 8;                     // 6250 dst nodes per slice
constexpr int GA = (NN + 63) / 64;                // 782 gemm blocks / slab chunks
constexpr int AGGB = 8 * ((GA + 1) / 2);          // 3128 agg blocks (XCD-pinned)
constexpr int EPCAP = EE + 7 * NN + 16;           // padded edge slots + slack

typedef unsigned short u16;
typedef unsigned int   u32;
typedef __attribute__((ext_vector_type(8))) short short8;
typedef __attribute__((ext_vector_type(4))) float f32x4;

__device__ __forceinline__ float bf2f(u16 u) {
    union { float f; u32 i; } c; c.i = ((u32)u) << 16; return c.f;
}
__device__ __forceinline__ u16 f2bf(float f) {          // round-to-nearest-even
    union { float f; u32 i; } c; c.f = f;
    u32 r = c.i + 0x7fffu + ((c.i >> 16) & 1u);
    return (u16)(r >> 16);
}

// ---- merged: 8-way dst-sliced histogram (blocks < HB*8) + weight prep -----
// slice = b&7 == XCD under round-robin dispatch -> deg atomics L2-local.
__global__ void k_hist_prep(const int* __restrict__ edst, int* __restrict__ deg,
                            const float* __restrict__ W0, const float* __restrict__ cw,
                            const float* __restrict__ W1, u16* __restrict__ w0t,
                            u16* __restrict__ wft, u16* __restrict__ w1t, int E) {
    int b = blockIdx.x;
    if (b < HB * 8) {
        const int slice = b & 7;
        const int i = (b >> 3) * 256 + threadIdx.x;
        if (i >= E) return;
        const int d = edst[i];
        const int lo = slice * SLICE;
        if (d >= lo && d < lo + SLICE) atomicAdd(&deg[d], 1);
    } else {
        int i = (b - HB * 8) * 256 + threadIdx.x;
        if (i < 16384) {
            int n = i >> 7, k = i & 127;
            w0t[i] = f2bf(W0[k * 128 + n]);
        } else if (i < 16384 + 6 * 16384) {
            int r = i - 16384;
            int l = r >> 14; int t = r & 16383;
            int n = t >> 7, k = t & 127;
            float v = BETA_C * cw[l * 16384 + k * 128 + n]
                      + ((k == n) ? (1.f - BETA_C) : 0.f);
            wft[r] = f2bf(v);
        } else if (i < PREP_TOT) {
            int r = i - (16384 + 6 * 16384);
            int n = r >> 7, k = r & 127;
            w1t[r] = f2bf(W1[k * 64 + n]);
        }
    }
}

// ---------------- single-dispatch scan: publish-first parallel lookback -----
// Scans PADDED degrees ((deg+7)&~7); bucket fills real edges + zeroes pads.
__global__ __launch_bounds__(256) void k_scan_lb(const int* __restrict__ deg,
                                                 int* __restrict__ bsum,
                                                 int* __restrict__ offs,
                                                 int* __restrict__ cur) {
    __shared__ int sh[256];
    __shared__ int sw[4];
    const int c = blockIdx.x, tid = threadIdx.x;
    const int i = c * 256 + tid;
    int v = (i < NN) ? ((deg[i] + 7) & ~7) : 0;
    sh[tid] = v;
    __syncthreads();
#pragma unroll
    for (int o = 1; o < 256; o <<= 1) {
        int u = (tid >= o) ? sh[tid - o] : 0;
        __syncthreads();
        sh[tid] += u;
        __syncthreads();
    }
    if (tid == 255) atomicExch(&bsum[c], sh[255] + 1);   // publish (nonzero)
    int part = 0;
    for (int t = tid; t < c; t += 256) {                 // parallel lookback
        int b;
        do { b = atomicAdd(&bsum[t], 0); } while (b == 0);
        part += b - 1;
    }
#pragma unroll
    for (int o = 32; o > 0; o >>= 1) part += __shfl_down(part, o);
    if ((tid & 63) == 0) sw[tid >> 6] = part;
    __syncthreads();
    const int base = sw[0] + sw[1] + sw[2] + sw[3];
    const int ex = base + sh[tid] - v;
    if (i < NN) {
        offs[i] = ex;
        cur[i]  = ex;
        if (i == NN - 1) offs[NN] = ex + v;
    }
}

// ---- layer-0 GEMM tile body (x fp32 row-major -> relu(x@W0+b0) bf16 slab) --
__device__ __forceinline__ void gemm0_tile(int t, const float* __restrict__ x,
                                           const u16* __restrict__ w0t,
                                           const float* __restrict__ b0,
                                           u16* __restrict__ x0s) {
    const int lane = threadIdx.x & 63;
    const int wave = threadIdx.x >> 6;
    const int q = lane >> 4;
    const int m16 = lane & 15;
    const int node = t * 64 + wave * 16 + m16;
    const int nload = node < NN ? node : NN - 1;

    short8 zf[4];
    const float* xp = x + (size_t)nload * 128 + q * 8;
#pragma unroll
    for (int s = 0; s < 4; ++s) {
        float4 u0 = *(const float4*)(xp + s * 32);
        float4 u1 = *(const float4*)(xp + s * 32 + 4);
        short8 z;
        z[0] = (short)f2bf(u0.x); z[1] = (short)f2bf(u0.y);
        z[2] = (short)f2bf(u0.z); z[3] = (short)f2bf(u0.w);
        z[4] = (short)f2bf(u1.x); z[5] = (short)f2bf(u1.y);
        z[6] = (short)f2bf(u1.z); z[7] = (short)f2bf(u1.w);
        zf[s] = z;
    }

    f32x4 acc[8];
#pragma unroll
    for (int c = 0; c < 8; ++c) {
        f32x4 a = {0.f, 0.f, 0.f, 0.f};
        const u16* wp = w0t + (size_t)(c * 16 + m16) * 128 + q * 8;
#pragma unroll
        for (int s = 0; s < 4; ++s) {
            short8 wf = *(const short8*)(wp + s * 32);
            a = __builtin_amdgcn_mfma_f32_16x16x32_bf16(wf, zf[s], a, 0, 0, 0);
        }
        acc[c] = a;
    }

    if (node < NN) {
#pragma unroll
        for (int c = 0; c < 8; ++c) {
            const int f0 = c * 16 + q * 4;
            float4 bv = *(const float4*)(b0 + f0);
            float v0 = acc[c][0] + bv.x; v0 = v0 > 0.f ? v0 : 0.f;
            float v1 = acc[c][1] + bv.y; v1 = v1 > 0.f ? v1 : 0.f;
            float v2 = acc[c][2] + bv.z; v2 = v2 > 0.f ? v2 : 0.f;
            float v3 = acc[c][3] + bv.w; v3 = v3 > 0.f ? v3 : 0.f;
            ushort4 o;
            o.x = f2bf(v0); o.y = f2bf(v1); o.z = f2bf(v2); o.w = f2bf(v3);
            *(ushort4*)(x0s + (size_t)(f0 >> 5) * NN * 32
                        + (size_t)node * 32 + (f0 & 31)) = o;
        }
    }
}

// -- merged: 8-way dst-sliced bucket + layer-0 GEMM + ep pad-zero (indep) ----
// slice = b&7 == XCD under round-robin dispatch -> cur/ep writes L2-local.
// Pad-zero range (last NB blocks): thread i zeroes ep[offs[i]+deg[i] ..
// offs[i+1]) — disjoint from atomic fills [offs[i], offs[i]+deg[i]).
__global__ __launch_bounds__(256) void k_bucket_g0(const int* __restrict__ src,
                                                   const int* __restrict__ dst,
                                                   const float* __restrict__ w,
                                                   int* __restrict__ cur,
                                                   u32* __restrict__ ep,
                                                   const float* __restrict__ x,
                                                   const u16* __restrict__ w0t,
                                                   const float* __restrict__ b0,
                                                   u16* __restrict__ x0s,
                                                   const int* __restrict__ offs,
                                                   const int* __restrict__ deg,
                                                   int E) {
    const int b = blockIdx.x;
    if (b < HB * 8) {
        const int slice = b & 7;
        const int i = (b >> 3) * 256 + threadIdx.x;
        if (i >= E) return;
        const int d = dst[i];
        const int lo = slice * SLICE;
        if (d >= lo && d < lo + SLICE) {
            int pos = atomicAdd(&cur[d], 1);
            ep[pos] = ((u32)f2bf(w[i]) << 16) | (u32)src[i];
        }
    } else if (b < HB * 8 + GA) {
        gemm0_tile(b - HB * 8, x, w0t, b0, x0s);
    } else {
        const int i = (b - HB * 8 - GA) * 256 + threadIdx.x;
        if (i < NN) {
            const int e0 = offs[i] + deg[i];
            const int e1 = offs[i + 1];
            for (int j = e0; j < e1; ++j) ep[j] = 0;     // pad slots: w=0,src=0
        }
    }
}

// ------- XCD-pinned slab aggregate + z-fold (R23 form — FROZEN) -------------
// Slab layout F[s][n][32] bf16; slab=(bid&7)>>1 -> XCD pair owns one 3.2MB
// slab (L2-resident). Wave = 16 consecutive nodes x 4 lanes (uint4 row part).
// Ranges exact multiples of 8 (R22 padding; pads w=0 -> +0.0f exact).
// Round k+1's ep loads issue before round k's gathers retire.
#define AGG_FMA8()                                                            \
    _Pragma("unroll")                                                         \
    for (int j = 0; j < 8; ++j) {                                             \
        float w = bf2f((u16)(r[j] >> 16));                                    \
        a0 += w * bf2f((u16)v[j].x);  a1 += w * bf2f((u16)(v[j].x >> 16));    \
        a2 += w * bf2f((u16)v[j].y);  a3 += w * bf2f((u16)(v[j].y >> 16));    \
        a4 += w * bf2f((u16)v[j].z);  a5 += w * bf2f((u16)(v[j].z >> 16));    \
        a6 += w * bf2f((u16)v[j].w);  a7 += w * bf2f((u16)(v[j].w >> 16));    \
    }

__global__ __launch_bounds__(256) void k_agg_z(const int* __restrict__ offs,
                                               const u32* __restrict__ ep,
                                               const u16* __restrict__ hs,
                                               const u16* __restrict__ x0s,
                                               u16* __restrict__ zs) {
    const int bid = blockIdx.x;
    const int s     = (bid & 7) >> 1;
    const int chunk = ((bid >> 3) << 1) | (bid & 1);     // 0..781
    const int lane = threadIdx.x & 63;
    const int wave = threadIdx.x >> 6;
    const int g  = lane >> 2;          // node group 0..15
    const int f4 = lane & 3;           // uint4 index within 64B slab row
    const int n  = chunk * 64 + wave * 16 + g;
    const int nc = n < NN ? n : NN - 1;
    const uint4* table = (const uint4*)(hs + (size_t)s * NN * 32);

    const int beg = offs[nc], end = offs[nc + 1];
    float a0 = 0.f, a1 = 0.f, a2 = 0.f, a3 = 0.f;
    float a4 = 0.f, a5 = 0.f, a6 = 0.f, a7 = 0.f;
    int e = beg;
    if (e + 7 < end) {
        u32 r[8];
#pragma unroll
        for (int j = 0; j < 8; ++j) r[j] = ep[e + j];
        e += 8;
        for (; e + 7 < end; e += 8) {
            u32 rn[8];
#pragma unroll
            for (int j = 0; j < 8; ++j) rn[j] = ep[e + j];   // prefetch round k+1
            uint4 v[8];
#pragma unroll
            for (int j = 0; j < 8; ++j)
                v[j] = table[(size_t)(r[j] & 0xffffu) * 4 + f4];
            AGG_FMA8();
#pragma unroll
            for (int j = 0; j < 8; ++j) r[j] = rn[j];
        }
        {   // epilogue: last prefetched group
            uint4 v[8];
#pragma unroll
            for (int j = 0; j < 8; ++j)
                v[j] = table[(size_t)(r[j] & 0xffffu) * 4 + f4];
            AGG_FMA8();
        }
    }
    for (; e < end; ++e) {             // correctness net (0 iters with padding)
        u32 r = ep[e];
        uint4 v = table[(size_t)(r & 0xffffu) * 4 + f4];
        float w = bf2f((u16)(r >> 16));
        a0 += w * bf2f((u16)v.x);  a1 += w * bf2f((u16)(v.x >> 16));
        a2 += w * bf2f((u16)v.y);  a3 += w * bf2f((u16)(v.y >> 16));
        a4 += w * bf2f((u16)v.z);  a5 += w * bf2f((u16)(v.z >> 16));
        a6 += w * bf2f((u16)v.w);  a7 += w * bf2f((u16)(v.w >> 16));
    }
    if (n < NN) {
        const size_t idx = (size_t)s * NN * 4 + (size_t)n * 4 + f4;   // uint4 units
        uint4 xv = ((const uint4*)x0s)[idx];
        float z0 = (1.f - ALPHA) * a0 + ALPHA * bf2f((u16)xv.x);
        float z1 = (1.f - ALPHA) * a1 + ALPHA * bf2f((u16)(xv.x >> 16));
        float z2 = (1.f - ALPHA) * a2 + ALPHA * bf2f((u16)xv.y);
        float z3 = (1.f - ALPHA) * a3 + ALPHA * bf2f((u16)(xv.y >> 16));
        float z4 = (1.f - ALPHA) * a4 + ALPHA * bf2f((u16)xv.z);
        float z5 = (1.f - ALPHA) * a5 + ALPHA * bf2f((u16)(xv.z >> 16));
        float z6 = (1.f - ALPHA) * a6 + ALPHA * bf2f((u16)xv.w);
        float z7 = (1.f - ALPHA) * a7 + ALPHA * bf2f((u16)(xv.w >> 16));
        uint4 o;
        o.x = (u32)f2bf(z0) | ((u32)f2bf(z1) << 16);
        o.y = (u32)f2bf(z2) | ((u32)f2bf(z3) << 16);
        o.z = (u32)f2bf(z4) | ((u32)f2bf(z5) << 16);
        o.w = (u32)f2bf(z6) | ((u32)f2bf(z7) << 16);
        ((uint4*)zs)[idx] = o;
    }
}

// ---------------- conv MFMA GEMM: h' = relu(z @ Wfold), slab layout ---------
__global__ __launch_bounds__(256) void k_gemm_conv(const u16* __restrict__ z,
                                                   const u16* __restrict__ Wt,
                                                   u16* __restrict__ hout) {
    const int lane = threadIdx.x & 63;
    const int wave = threadIdx.x >> 6;
    const int q = lane >> 4;
    const int m16 = lane & 15;
    const int node = blockIdx.x * 64 + wave * 16 + m16;
    const int nload = node < NN ? node : NN - 1;

    short8 zf[4];
#pragma unroll
    for (int s = 0; s < 4; ++s)
        zf[s] = *(const short8*)(z + (size_t)s * NN * 32 + (size_t)nload * 32 + q * 8);

    f32x4 acc[8];
#pragma unroll
    for (int c = 0; c < 8; ++c) {
        f32x4 a = {0.f, 0.f, 0.f, 0.f};
        const u16* wp = Wt + (size_t)(c * 16 + m16) * 128 + q * 8;
#pragma unroll
        for (int s = 0; s < 4; ++s) {
            short8 wf = *(const short8*)(wp + s * 32);
            a = __builtin_amdgcn_mfma_f32_16x16x32_bf16(wf, zf[s], a, 0, 0, 0);
        }
        acc[c] = a;
    }

    if (node < NN) {
#pragma unroll
        for (int c = 0; c < 8; ++c) {
            const int f0 = c * 16 + q * 4;
            float v0 = acc[c][0] > 0.f ? acc[c][0] : 0.f;
            float v1 = acc[c][1] > 0.f ? acc[c][1] : 0.f;
            float v2 = acc[c][2] > 0.f ? acc[c][2] : 0.f;
            float v3 = acc[c][3] > 0.f ? acc[c][3] : 0.f;
            ushort4 o;
            o.x = f2bf(v0); o.y = f2bf(v1); o.z = f2bf(v2); o.w = f2bf(v3);
            *(ushort4*)(hout + (size_t)(f0 >> 5) * NN * 32
                        + (size_t)node * 32 + (f0 & 31)) = o;
        }
    }
}

// ---------------- fused last conv + final projection ----------------
__global__ __launch_bounds__(256) void k_gemm_last(const u16* __restrict__ z,
                                                   const u16* __restrict__ wf5,
                                                   const u16* __restrict__ w1t,
                                                   const float* __restrict__ b1,
                                                   float* __restrict__ out) {
    __shared__ __align__(16) u16 hl[4][16][136];   // +8 pad: conflict-free
    const int lane = threadIdx.x & 63;
    const int wave = threadIdx.x >> 6;
    const int q = lane >> 4;
    const int m16 = lane & 15;
    const int node = blockIdx.x * 64 + wave * 16 + m16;
    const int nload = node < NN ? node : NN - 1;

    short8 zf[4];
#pragma unroll
    for (int s = 0; s < 4; ++s)
        zf[s] = *(const short8*)(z + (size_t)s * NN * 32 + (size_t)nload * 32 + q * 8);

    // ---- h = relu(z @ Wfold5), bf16 into LDS
#pragma unroll
    for (int c = 0; c < 8; ++c) {
        f32x4 a = {0.f, 0.f, 0.f, 0.f};
        const u16* wp = wf5 + (size_t)(c * 16 + m16) * 128 + q * 8;
#pragma unroll
        for (int s = 0; s < 4; ++s) {
            short8 wf = *(const short8*)(wp + s * 32);
            a = __builtin_amdgcn_mfma_f32_16x16x32_bf16(wf, zf[s], a, 0, 0, 0);
        }
        float v0 = a[0] > 0.f ? a[0] : 0.f;
        float v1 = a[1] > 0.f ? a[1] : 0.f;
        float v2 = a[2] > 0.f ? a[2] : 0.f;
        float v3 = a[3] > 0.f ? a[3] : 0.f;
        ushort4 o;
        o.x = f2bf(v0); o.y = f2bf(v1); o.z = f2bf(v2); o.w = f2bf(v3);
        *(ushort4*)&hl[wave][m16][c * 16 + q * 4] = o;
    }
    __syncthreads();

    // ---- out = h @ W1 + b1
    short8 hf[4];
#pragma unroll
    for (int s = 0; s < 4; ++s)
        hf[s] = *(const short8*)&hl[wave][m16][s * 32 + q * 8];

#pragma unroll
    for (int c = 0; c < 4; ++c) {
        f32x4 a = {0.f, 0.f, 0.f, 0.f};
        const u16* wp = w1t + (size_t)(c * 16 + m16) * 128 + q * 8;
#pragma unroll
        for (int s = 0; s < 4; ++s) {
            short8 wf = *(const short8*)(wp + s * 32);
            a = __builtin_amdgcn_mfma_f32_16x16x32_bf16(wf, hf[s], a, 0, 0, 0);
        }
        if (node < NN) {
            const int f0 = c * 16 + q * 4;
            float4 bv = *(const float4*)(b1 + f0);
            float4 o;
            o.x = a[0] + bv.x; o.y = a[1] + bv.y;
            o.z = a[2] + bv.z; o.w = a[3] + bv.w;
            *(float4*)(out + (size_t)node * 64 + f0) = o;
        }
    }
}

// ---------------------------------------------------------------------------

extern "C" void kernel_launch(void* const* d_in, const int* in_sizes, int n_in,
                              void* d_out, int out_size, void* d_ws, size_t ws_size,
                              hipStream_t stream) {
    const float* x    = (const float*)d_in[0];
    const int*   esrc = (const int*)d_in[1];
    const int*   edst = (const int*)d_in[2];
    const float* ew   = (const float*)d_in[3];
    const float* W0   = (const float*)d_in[4];
    const float* b0   = (const float*)d_in[5];
    const float* W1   = (const float*)d_in[6];
    const float* b1   = (const float*)d_in[7];
    const float* cw   = (const float*)d_in[8];
    float* out = (float*)d_out;

    // workspace layout; slab buffers are [4][NN][32] bf16
    u32* ep4 = (u32*)d_ws;                         // EPCAP padded edge slots
    u16* x0s = (u16*)(ep4 + EPCAP);
    u16* hb1 = x0s + (size_t)4 * NN * 32;
    u16* hb2 = hb1 + (size_t)4 * NN * 32;
    u16* zsb = hb2 + (size_t)4 * NN * 32;
    u16* w0t = zsb + (size_t)4 * NN * 32;
    u16* wft = w0t + 128 * 128;
    u16* w1t = wft + 6 * 128 * 128;
    int* deg = (int*)(w1t + 64 * 128);
    int* bsum = deg + NN;
    int* offs = bsum + NB;
    int* cur = offs + NN + 1;

    // ---- CSR build + weight prep; bucket merged with layer-0 GEMM and
    //      ep pad-zeroing (R28: no ep memset dispatch)
    (void)hipMemsetAsync(deg, 0, (size_t)(NN + NB) * sizeof(int), stream);
    k_hist_prep<<<HB * 8 + PB, 256, 0, stream>>>(edst, deg, W0, cw, W1, w0t, wft, w1t, EE);
    k_scan_lb<<<NB, 256, 0, stream>>>(deg, bsum, offs, cur);
    k_bucket_g0<<<HB * 8 + GA + NB, 256, 0, stream>>>(esrc, edst, ew, cur, ep4,
                                                      x, w0t, b0, x0s, offs, deg, EE);

    // ---- convs 0..4: z = 0.9*agg(h) + 0.1*x0 ; h' = relu(z @ Wfold)
    const u16* hin = x0s;
    u16* houts[5] = {hb1, hb2, hb1, hb2, hb1};
    for (int i = 0; i < 5; ++i) {
        k_agg_z<<<AGGB, 256, 0, stream>>>(offs, ep4, hin, x0s, zsb);
        k_gemm_conv<<<GA, 256, 0, stream>>>(zsb, wft + (size_t)i * 16384, houts[i]);
        hin = houts[i];
    }

    // ---- conv 5 fused with final projection
    k_agg_z<<<AGGB, 256, 0, stream>>>(offs, ep4, hin, x0s, zsb);
    k_gemm_last<<<GA, 256, 0, stream>>>(zsb, wft + (size_t)5 * 16384, w1t, b1, out);
}